// Round 7
// baseline (226.419 us; speedup 1.0000x reference)
//
#include <hip/hip_runtime.h>

// Network_31945966748134: per-row MLP collapse.
//   h = relu(x . w_in); 9x relu(w_i*h) == h * prod(max(w_i,0)); softmax(h*w_out).
// Memory-bound: 134 MB read + 101 MB write.
// Round 7 split-hint version:
//   - x loads CACHED (harness restore makes x L3-resident; nt-load would
//     bypass/evict the hot lines and force HBM reads)
//   - output stores NON-TEMPORAL (write-once stream, keep L3 for x)
//   - approx rcp for the softmax normalize (exact div is ~10 VALU ops)
// Block of 256 threads owns 1024 consecutive rows; lane-contiguous float4
// loads; results staged in 12 KB LDS; 3 lane-contiguous nt float4 stores.

typedef float f32x4 __attribute__((ext_vector_type(4)));

#define ROWS_PER_BLOCK 1024

__global__ __launch_bounds__(256) void Network_31945966748134_kernel(
    const f32x4* __restrict__ xv,
    const float* __restrict__ w_in,
    const float* __restrict__ w_hidden,
    const float* __restrict__ w_out,
    f32x4* __restrict__ outv,
    int nrows)
{
    __shared__ float lds[ROWS_PER_BLOCK * 3];  // 12 KB

    // Wave-uniform weight loads (scalar path, cached).
    const float wi0 = w_in[0], wi1 = w_in[1], wi2 = w_in[2], wi3 = w_in[3];
    float c = 1.0f;
#pragma unroll
    for (int i = 0; i < 9; ++i) c *= fmaxf(w_hidden[i], 0.0f);
    const float wo0 = w_out[0], wo1 = w_out[1], wo2 = w_out[2];

    const int tid = threadIdx.x;
    const int base = blockIdx.x * ROWS_PER_BLOCK;

#pragma unroll
    for (int k = 0; k < 4; ++k) {
        const int lr = k * 256 + tid;          // local row 0..1023
        const int r = base + lr;
        if (r < nrows) {
            const f32x4 xs = xv[r];            // cached, coalesced (L3-hot)
            float h = xs.x * wi0 + xs.y * wi1 + xs.z * wi2 + xs.w * wi3;
            h = fmaxf(h, 0.0f) * c;
            const float l0 = h * wo0, l1 = h * wo1, l2 = h * wo2;
            const float m = fmaxf(fmaxf(l0, l1), l2);
            const float e0 = __expf(l0 - m);
            const float e1 = __expf(l1 - m);
            const float e2 = __expf(l2 - m);
            const float inv = __builtin_amdgcn_rcpf(e0 + e1 + e2);
            // stride-3 float writes: 2 lanes/bank max (free per m136)
            lds[lr * 3 + 0] = e0 * inv;
            lds[lr * 3 + 1] = e1 * inv;
            lds[lr * 3 + 2] = e2 * inv;
        }
    }
    __syncthreads();

    // Coalesced non-temporal write-back of the block's contiguous slice.
    const f32x4* __restrict__ lv = (const f32x4*)lds;
    const size_t out4base = (size_t)blockIdx.x * (ROWS_PER_BLOCK * 3 / 4);
    const int valid_floats = (min(nrows - base, ROWS_PER_BLOCK)) * 3;
#pragma unroll
    for (int k = 0; k < 3; ++k) {
        const int idx = k * 256 + tid;         // float4 index within block slice
        const int f0 = idx * 4;
        if (f0 + 4 <= valid_floats) {
            __builtin_nontemporal_store(lv[idx], &outv[out4base + idx]);
        } else if (f0 < valid_floats) {
            float* o = (float*)(outv + out4base + idx);
            for (int j = 0; j < valid_floats - f0; ++j) o[j] = lds[f0 + j];
        }
    }
}

extern "C" void kernel_launch(void* const* d_in, const int* in_sizes, int n_in,
                              void* d_out, int out_size, void* d_ws, size_t ws_size,
                              hipStream_t stream) {
    const float* x        = (const float*)d_in[0];
    const float* w_in     = (const float*)d_in[1];
    const float* w_hidden = (const float*)d_in[2];
    const float* w_out    = (const float*)d_in[3];
    float* out = (float*)d_out;

    const int nrows = in_sizes[0] / 4;  // x is [B,4]
    const int grid = (nrows + ROWS_PER_BLOCK - 1) / ROWS_PER_BLOCK;
    Network_31945966748134_kernel<<<grid, 256, 0, stream>>>(
        (const f32x4*)x, w_in, w_hidden, w_out, (f32x4*)out, nrows);
}

// Round 8
// 215.692 us; speedup vs baseline: 1.0497x; 1.0497x over previous
//
#include <hip/hip_runtime.h>

// Network_31945966748134: per-row MLP collapse.
//   h = relu(x . w_in); 9x relu(w_i*h) == h * prod(max(w_i,0)); softmax(h*w_out).
// Memory-bound: 134 MB read + 101 MB write.
// R8 = R6 config restored (nt-load + nt-store) + rcpf from R7.
//   Mechanism: harness re-poisons 512 MB ws right before launch -> L3 is full
//   of dirty poison lines; cached x-reads would allocate L3 lines and force
//   dirty writebacks (R7: +10 us). nt on BOTH streams avoids L3 allocation.
// Block of 256 threads owns 1024 consecutive rows; lane-contiguous float4
// loads; results staged in 12 KB LDS; 3 lane-contiguous nt float4 stores.

typedef float f32x4 __attribute__((ext_vector_type(4)));

#define ROWS_PER_BLOCK 1024

__global__ __launch_bounds__(256) void Network_31945966748134_kernel(
    const f32x4* __restrict__ xv,
    const float* __restrict__ w_in,
    const float* __restrict__ w_hidden,
    const float* __restrict__ w_out,
    f32x4* __restrict__ outv,
    int nrows)
{
    __shared__ float lds[ROWS_PER_BLOCK * 3];  // 12 KB

    // Wave-uniform weight loads (scalar path, cached).
    const float wi0 = w_in[0], wi1 = w_in[1], wi2 = w_in[2], wi3 = w_in[3];
    float c = 1.0f;
#pragma unroll
    for (int i = 0; i < 9; ++i) c *= fmaxf(w_hidden[i], 0.0f);
    const float wo0 = w_out[0], wo1 = w_out[1], wo2 = w_out[2];

    const int tid = threadIdx.x;
    const int base = blockIdx.x * ROWS_PER_BLOCK;

#pragma unroll
    for (int k = 0; k < 4; ++k) {
        const int lr = k * 256 + tid;          // local row 0..1023
        const int r = base + lr;
        if (r < nrows) {
            const f32x4 xs = __builtin_nontemporal_load(&xv[r]);  // coalesced
            float h = xs.x * wi0 + xs.y * wi1 + xs.z * wi2 + xs.w * wi3;
            h = fmaxf(h, 0.0f) * c;
            const float l0 = h * wo0, l1 = h * wo1, l2 = h * wo2;
            const float m = fmaxf(fmaxf(l0, l1), l2);
            const float e0 = __expf(l0 - m);
            const float e1 = __expf(l1 - m);
            const float e2 = __expf(l2 - m);
            const float inv = __builtin_amdgcn_rcpf(e0 + e1 + e2);
            // stride-3 float writes: 2 lanes/bank max (free per m136)
            lds[lr * 3 + 0] = e0 * inv;
            lds[lr * 3 + 1] = e1 * inv;
            lds[lr * 3 + 2] = e2 * inv;
        }
    }
    __syncthreads();

    // Coalesced non-temporal write-back of the block's contiguous slice.
    const f32x4* __restrict__ lv = (const f32x4*)lds;
    const size_t out4base = (size_t)blockIdx.x * (ROWS_PER_BLOCK * 3 / 4);
    const int valid_floats = (min(nrows - base, ROWS_PER_BLOCK)) * 3;
#pragma unroll
    for (int k = 0; k < 3; ++k) {
        const int idx = k * 256 + tid;         // float4 index within block slice
        const int f0 = idx * 4;
        if (f0 + 4 <= valid_floats) {
            __builtin_nontemporal_store(lv[idx], &outv[out4base + idx]);
        } else if (f0 < valid_floats) {
            float* o = (float*)(outv + out4base + idx);
            for (int j = 0; j < valid_floats - f0; ++j) o[j] = lds[f0 + j];
        }
    }
}

extern "C" void kernel_launch(void* const* d_in, const int* in_sizes, int n_in,
                              void* d_out, int out_size, void* d_ws, size_t ws_size,
                              hipStream_t stream) {
    const float* x        = (const float*)d_in[0];
    const float* w_in     = (const float*)d_in[1];
    const float* w_hidden = (const float*)d_in[2];
    const float* w_out    = (const float*)d_in[3];
    float* out = (float*)d_out;

    const int nrows = in_sizes[0] / 4;  // x is [B,4]
    const int grid = (nrows + ROWS_PER_BLOCK - 1) / ROWS_PER_BLOCK;
    Network_31945966748134_kernel<<<grid, 256, 0, stream>>>(
        (const f32x4*)x, w_in, w_hidden, w_out, (f32x4*)out, nrows);
}

// Round 9
// 214.855 us; speedup vs baseline: 1.0538x; 1.0039x over previous
//
#include <hip/hip_runtime.h>

// Network_31945966748134: per-row MLP collapse.
//   h = relu(x . w_in); 9x relu(w_i*h) == h * prod(max(w_i,0)); softmax(h*w_out).
// Memory-bound: 134 MB read + 101 MB write. nt on both streams (R6/R8 win:
// harness re-poisons 512 MB ws before each replay -> L3 full of dirty lines;
// cached x-reads allocate L3 and force writebacks, +10 us).
// R9: guard-free fast path. Grid*1024 == nrows exactly, so the per-row
// if-guard is dead — but it control-depends every global load (compiler
// can't speculate loads across branches), serializing the 4 loads at HBM
// latency. Fast path issues all 4 nt loads back-to-back (4-deep pipeline,
// single drain), then computes, then 3 guard-free nt stores.

typedef float f32x4 __attribute__((ext_vector_type(4)));

#define ROWS_PER_BLOCK 1024

__global__ __launch_bounds__(256) void Network_31945966748134_kernel(
    const f32x4* __restrict__ xv,
    const float* __restrict__ w_in,
    const float* __restrict__ w_hidden,
    const float* __restrict__ w_out,
    f32x4* __restrict__ outv,
    int nrows)
{
    __shared__ float lds[ROWS_PER_BLOCK * 3];  // 12 KB

    // Wave-uniform weight loads (scalar path, cached).
    const float wi0 = w_in[0], wi1 = w_in[1], wi2 = w_in[2], wi3 = w_in[3];
    float c = 1.0f;
#pragma unroll
    for (int i = 0; i < 9; ++i) c *= fmaxf(w_hidden[i], 0.0f);
    const float wo0 = w_out[0], wo1 = w_out[1], wo2 = w_out[2];

    const int tid = threadIdx.x;
    const int base = blockIdx.x * ROWS_PER_BLOCK;
    const f32x4* __restrict__ lv = (const f32x4*)lds;
    const size_t out4base = (size_t)blockIdx.x * (ROWS_PER_BLOCK * 3 / 4);

    if (base + ROWS_PER_BLOCK <= nrows) {
        // ---- fast path: no guards, loads issued 4-deep ----
        f32x4 xs[4];
#pragma unroll
        for (int k = 0; k < 4; ++k)
            xs[k] = __builtin_nontemporal_load(&xv[base + k * 256 + tid]);
#pragma unroll
        for (int k = 0; k < 4; ++k) {
            const int lr = k * 256 + tid;
            float h = xs[k].x * wi0 + xs[k].y * wi1 + xs[k].z * wi2 + xs[k].w * wi3;
            h = fmaxf(h, 0.0f) * c;
            const float l0 = h * wo0, l1 = h * wo1, l2 = h * wo2;
            const float m = fmaxf(fmaxf(l0, l1), l2);
            const float e0 = __expf(l0 - m);
            const float e1 = __expf(l1 - m);
            const float e2 = __expf(l2 - m);
            const float inv = __builtin_amdgcn_rcpf(e0 + e1 + e2);
            lds[lr * 3 + 0] = e0 * inv;   // stride-3: <=2 lanes/bank (free)
            lds[lr * 3 + 1] = e1 * inv;
            lds[lr * 3 + 2] = e2 * inv;
        }
        __syncthreads();
#pragma unroll
        for (int k = 0; k < 3; ++k) {
            const int idx = k * 256 + tid;
            __builtin_nontemporal_store(lv[idx], &outv[out4base + idx]);
        }
    } else {
        // ---- ragged tail path (unused at B=8.4M, kept for generality) ----
#pragma unroll
        for (int k = 0; k < 4; ++k) {
            const int lr = k * 256 + tid;
            const int r = base + lr;
            if (r < nrows) {
                const f32x4 x4 = __builtin_nontemporal_load(&xv[r]);
                float h = x4.x * wi0 + x4.y * wi1 + x4.z * wi2 + x4.w * wi3;
                h = fmaxf(h, 0.0f) * c;
                const float l0 = h * wo0, l1 = h * wo1, l2 = h * wo2;
                const float m = fmaxf(fmaxf(l0, l1), l2);
                const float e0 = __expf(l0 - m);
                const float e1 = __expf(l1 - m);
                const float e2 = __expf(l2 - m);
                const float inv = __builtin_amdgcn_rcpf(e0 + e1 + e2);
                lds[lr * 3 + 0] = e0 * inv;
                lds[lr * 3 + 1] = e1 * inv;
                lds[lr * 3 + 2] = e2 * inv;
            }
        }
        __syncthreads();
        const int valid_floats = (min(nrows - base, ROWS_PER_BLOCK)) * 3;
#pragma unroll
        for (int k = 0; k < 3; ++k) {
            const int idx = k * 256 + tid;
            const int f0 = idx * 4;
            if (f0 + 4 <= valid_floats) {
                __builtin_nontemporal_store(lv[idx], &outv[out4base + idx]);
            } else if (f0 < valid_floats) {
                float* o = (float*)(outv + out4base + idx);
                for (int j = 0; j < valid_floats - f0; ++j) o[j] = lds[f0 + j];
            }
        }
    }
}

extern "C" void kernel_launch(void* const* d_in, const int* in_sizes, int n_in,
                              void* d_out, int out_size, void* d_ws, size_t ws_size,
                              hipStream_t stream) {
    const float* x        = (const float*)d_in[0];
    const float* w_in     = (const float*)d_in[1];
    const float* w_hidden = (const float*)d_in[2];
    const float* w_out    = (const float*)d_in[3];
    float* out = (float*)d_out;

    const int nrows = in_sizes[0] / 4;  // x is [B,4]
    const int grid = (nrows + ROWS_PER_BLOCK - 1) / ROWS_PER_BLOCK;
    Network_31945966748134_kernel<<<grid, 256, 0, stream>>>(
        (const f32x4*)x, w_in, w_hidden, w_out, (f32x4*)out, nrows);
}